// Round 1
// baseline (2288.477 us; speedup 1.0000x reference)
//
#include <hip/hip_runtime.h>
#include <hip/hip_bf16.h>

// LightGCN: 3 layers of scatter-add SpMM on 200000x64 f32 embeddings, 3.2M edges.
// Baseline: one wave per edge, lane = embedding element, atomicAdd scatter.

constexpr int NUM_USERS = 100000;
constexpr int NUM_ITEMS = 100000;
constexpr int N_NODES   = NUM_USERS + NUM_ITEMS;   // 200000
constexpr int EMB       = 64;
constexpr int N_EDGES   = 3200000;
constexpr int N_LAYERS  = 3;

constexpr int TOT4 = N_NODES * EMB / 4;            // 3.2M float4
constexpr int NU4  = NUM_USERS * EMB / 4;          // 1.6M float4

// cur = concat(user, item); acc(d_out) = 0
__global__ void concat_init(const float4* __restrict__ u,
                            const float4* __restrict__ it,
                            float4* __restrict__ cur,
                            float4* __restrict__ acc) {
    int i = blockIdx.x * blockDim.x + threadIdx.x;
    if (i >= TOT4) return;
    cur[i] = (i < NU4) ? u[i] : it[i - NU4];
    acc[i] = make_float4(0.f, 0.f, 0.f, 0.f);
}

// One 64-lane wave per edge; lane = embedding element.
__global__ void spmm_scatter(const int*   __restrict__ row,
                             const int*   __restrict__ col,
                             const float* __restrict__ w,
                             const float* __restrict__ x,
                             float*       __restrict__ y) {
    int edge = blockIdx.x * (blockDim.x >> 6) + (threadIdx.x >> 6);
    int lane = threadIdx.x & 63;
    if (edge >= N_EDGES) return;
    int   r  = row[edge];
    int   c  = col[edge];
    float wt = w[edge];
    float v  = wt * x[c * EMB + lane];
    atomicAdd(&y[r * EMB + lane], v);
}

// acc += nxt / N_LAYERS
__global__ void acc_scale(float4* __restrict__ acc,
                          const float4* __restrict__ nxt) {
    int i = blockIdx.x * blockDim.x + threadIdx.x;
    if (i >= TOT4) return;
    float4 a = acc[i];
    float4 n = nxt[i];
    constexpr float s = 1.0f / (float)N_LAYERS;
    a.x += n.x * s;
    a.y += n.y * s;
    a.z += n.z * s;
    a.w += n.w * s;
    acc[i] = a;
}

extern "C" void kernel_launch(void* const* d_in, const int* in_sizes, int n_in,
                              void* d_out, int out_size, void* d_ws, size_t ws_size,
                              hipStream_t stream) {
    const float* user_emb = (const float*)d_in[0];
    const float* item_emb = (const float*)d_in[1];
    const float* edge_w   = (const float*)d_in[2];
    const int*   edge_row = (const int*)d_in[3];
    const int*   edge_col = (const int*)d_in[4];
    float*       out      = (float*)d_out;

    float* buf0 = (float*)d_ws;
    float* buf1 = buf0 + (size_t)N_NODES * EMB;

    // init: cur = concat, acc = 0
    {
        int blk = 256;
        int grid = (TOT4 + blk - 1) / blk;
        concat_init<<<grid, blk, 0, stream>>>(
            (const float4*)user_emb, (const float4*)item_emb,
            (float4*)buf0, (float4*)out);
    }

    float* cur = buf0;
    float* nxt = buf1;
    for (int l = 0; l < N_LAYERS; ++l) {
        hipMemsetAsync(nxt, 0, (size_t)N_NODES * EMB * sizeof(float), stream);

        // 4 edges per 256-thread block (1 wave per edge)
        int edges_per_block = 256 / 64;
        int grid = (N_EDGES + edges_per_block - 1) / edges_per_block;
        spmm_scatter<<<grid, 256, 0, stream>>>(edge_row, edge_col, edge_w, cur, nxt);

        int blk = 256;
        int grid2 = (TOT4 + blk - 1) / blk;
        acc_scale<<<grid2, blk, 0, stream>>>((float4*)out, (const float4*)nxt);

        float* tmp = cur; cur = nxt; nxt = tmp;
    }
}

// Round 2
// 1089.340 us; speedup vs baseline: 2.1008x; 2.1008x over previous
//
#include <hip/hip_runtime.h>
#include <hip/hip_bf16.h>

// LightGCN: 3 layers of SpMM on 200000x64 f32 embeddings, 3.2M edges.
// R1: build CSR in-kernel (histogram + scan + scatter), then gather-based
// SpMM: one wave per output row, register accumulate, streaming writes.
// Fusions: layer0 reads user/item directly; acc += ego/3 in epilogue;
// last layer skips writing ego.

constexpr int NUM_USERS = 100000;
constexpr int NUM_ITEMS = 100000;
constexpr int N_NODES   = NUM_USERS + NUM_ITEMS;   // 200000
constexpr int EMB       = 64;
constexpr int N_EDGES   = 3200000;

constexpr int SCAN_BLOCK = 256;
constexpr int SCAN_ELEMS = 1024;                   // 4 per thread
constexpr int NUM_SCAN_BLOCKS = (N_NODES + SCAN_ELEMS - 1) / SCAN_ELEMS; // 196

// ---------------- CSR build ----------------

__global__ void histogram(const int* __restrict__ row, int* __restrict__ cnt) {
    int e = blockIdx.x * blockDim.x + threadIdx.x;
    if (e >= N_EDGES) return;
    atomicAdd(&cnt[row[e]], 1);
}

__global__ void scan_reduce(const int* __restrict__ cnt, int* __restrict__ partials) {
    __shared__ int lds[SCAN_BLOCK];
    int b = blockIdx.x, t = threadIdx.x;
    int base = b * SCAN_ELEMS + t * 4;
    int s = 0;
#pragma unroll
    for (int k = 0; k < 4; ++k) {
        int i = base + k;
        if (i < N_NODES) s += cnt[i];
    }
    lds[t] = s;
    __syncthreads();
    for (int off = SCAN_BLOCK / 2; off > 0; off >>= 1) {
        if (t < off) lds[t] += lds[t + off];
        __syncthreads();
    }
    if (t == 0) partials[b] = lds[0];
}

__global__ void scan_partials(int* partials) {
    __shared__ int lds[SCAN_BLOCK];
    int t = threadIdx.x;
    int v = (t < NUM_SCAN_BLOCKS) ? partials[t] : 0;
    lds[t] = v;
    __syncthreads();
    for (int off = 1; off < SCAN_BLOCK; off <<= 1) {
        int x = (t >= off) ? lds[t - off] : 0;
        __syncthreads();
        lds[t] += x;
        __syncthreads();
    }
    if (t < NUM_SCAN_BLOCKS) partials[t] = lds[t] - v;   // exclusive
}

__global__ void scan_final(const int* __restrict__ cnt, const int* __restrict__ partials,
                           int* __restrict__ row_start, int* __restrict__ cursor) {
    __shared__ int lds[SCAN_BLOCK];
    int b = blockIdx.x, t = threadIdx.x;
    int base = b * SCAN_ELEMS + t * 4;
    int v[4], pre[4];
    int s = 0;
#pragma unroll
    for (int k = 0; k < 4; ++k) {
        int i = base + k;
        v[k] = (i < N_NODES) ? cnt[i] : 0;
        pre[k] = s;
        s += v[k];
    }
    lds[t] = s;
    __syncthreads();
    int incl = s;
    for (int off = 1; off < SCAN_BLOCK; off <<= 1) {
        int x = (t >= off) ? lds[t - off] : 0;
        __syncthreads();
        lds[t] += x;
        __syncthreads();
    }
    incl = lds[t];
    int thread_excl = incl - s;
    int blockbase = partials[b];
#pragma unroll
    for (int k = 0; k < 4; ++k) {
        int i = base + k;
        if (i < N_NODES) {
            int val = blockbase + thread_excl + pre[k];
            row_start[i] = val;
            cursor[i]    = val;
        }
    }
    if (b == 0 && t == 0) row_start[N_NODES] = N_EDGES;
}

__global__ void scatter_edges(const int* __restrict__ row, const int* __restrict__ col,
                              const float* __restrict__ w,
                              int* __restrict__ cursor, int2* __restrict__ sorted) {
    int e = blockIdx.x * blockDim.x + threadIdx.x;
    if (e >= N_EDGES) return;
    int r = row[e];
    int pos = atomicAdd(&cursor[r], 1);
    sorted[pos] = make_int2(col[e], __float_as_int(w[e]));
}

// ---------------- SpMM (CSR, one wave per row) ----------------

template<bool FIRST, bool WRITE_Y>
__global__ void spmm_csr(const int* __restrict__ row_start,
                         const int2* __restrict__ sorted,
                         const float* __restrict__ srcA,   // node < NUM_USERS
                         const float* __restrict__ srcB,   // node >= NUM_USERS (pre-offset)
                         float* __restrict__ y,
                         float* __restrict__ acc) {
    int r    = blockIdx.x * (blockDim.x >> 6) + (threadIdx.x >> 6);
    int lane = threadIdx.x & 63;
    if (r >= N_NODES) return;
    int s0 = row_start[r];
    int s1 = row_start[r + 1];
    float a = 0.f;
    for (int base = s0; base < s1; base += 64) {
        int idx = base + lane;
        int2 e = make_int2(0, 0);
        if (idx < s1) e = sorted[idx];
        int n = s1 - base;
        if (n > 64) n = 64;
        for (int j = 0; j < n; ++j) {
            int   c  = __shfl(e.x, j);
            float wt = __int_as_float(__shfl(e.y, j));
            const float* src = (c < NUM_USERS) ? srcA : srcB;
            a = fmaf(wt, src[(size_t)c * EMB + lane], a);
        }
    }
    size_t o = (size_t)r * EMB + lane;
    if (WRITE_Y) y[o] = a;
    constexpr float sc = 1.0f / 3.0f;
    if (FIRST) acc[o] = a * sc;
    else       acc[o] += a * sc;
}

// ---------------- fallback (baseline atomic path) ----------------

constexpr int TOT4 = N_NODES * EMB / 4;
constexpr int NU4  = NUM_USERS * EMB / 4;

__global__ void concat_init(const float4* __restrict__ u, const float4* __restrict__ it,
                            float4* __restrict__ cur, float4* __restrict__ acc) {
    int i = blockIdx.x * blockDim.x + threadIdx.x;
    if (i >= TOT4) return;
    cur[i] = (i < NU4) ? u[i] : it[i - NU4];
    acc[i] = make_float4(0.f, 0.f, 0.f, 0.f);
}

__global__ void spmm_scatter(const int* __restrict__ row, const int* __restrict__ col,
                             const float* __restrict__ w, const float* __restrict__ x,
                             float* __restrict__ y) {
    int edge = blockIdx.x * (blockDim.x >> 6) + (threadIdx.x >> 6);
    int lane = threadIdx.x & 63;
    if (edge >= N_EDGES) return;
    int   r  = row[edge];
    int   c  = col[edge];
    float wt = w[edge];
    atomicAdd(&y[r * EMB + lane], wt * x[c * EMB + lane]);
}

__global__ void acc_scale(float4* __restrict__ acc, const float4* __restrict__ nxt) {
    int i = blockIdx.x * blockDim.x + threadIdx.x;
    if (i >= TOT4) return;
    float4 a = acc[i];
    float4 n = nxt[i];
    constexpr float s = 1.0f / 3.0f;
    a.x += n.x * s; a.y += n.y * s; a.z += n.z * s; a.w += n.w * s;
    acc[i] = a;
}

// ---------------- launch ----------------

extern "C" void kernel_launch(void* const* d_in, const int* in_sizes, int n_in,
                              void* d_out, int out_size, void* d_ws, size_t ws_size,
                              hipStream_t stream) {
    const float* user_emb = (const float*)d_in[0];
    const float* item_emb = (const float*)d_in[1];
    const float* edge_w   = (const float*)d_in[2];
    const int*   edge_row = (const int*)d_in[3];
    const int*   edge_col = (const int*)d_in[4];
    float*       out      = (float*)d_out;

    const size_t NBUF = (size_t)N_NODES * EMB;     // 12.8M floats

    float* buf0 = (float*)d_ws;
    float* buf1 = buf0 + NBUF;

    // CSR-path extra scratch after the two ping-pong buffers
    char*  p        = (char*)(buf1 + NBUF);
    int2*  sorted   = (int2*)p;                     p += (size_t)N_EDGES * sizeof(int2);
    int*   cnt      = (int*)p;                      p += (size_t)N_NODES * sizeof(int);
    int*   row_start= (int*)p;                      p += (size_t)(N_NODES + 1) * sizeof(int);
    int*   cursor   = (int*)p;                      p += (size_t)N_NODES * sizeof(int);
    int*   partials = (int*)p;                      p += (size_t)SCAN_BLOCK * sizeof(int);
    size_t need = (size_t)((char*)p - (char*)d_ws);

    if (ws_size >= need) {
        // ---- CSR build ----
        hipMemsetAsync(cnt, 0, (size_t)N_NODES * sizeof(int), stream);
        histogram<<<(N_EDGES + 255) / 256, 256, 0, stream>>>(edge_row, cnt);
        scan_reduce<<<NUM_SCAN_BLOCKS, SCAN_BLOCK, 0, stream>>>(cnt, partials);
        scan_partials<<<1, SCAN_BLOCK, 0, stream>>>(partials);
        scan_final<<<NUM_SCAN_BLOCKS, SCAN_BLOCK, 0, stream>>>(cnt, partials, row_start, cursor);
        scatter_edges<<<(N_EDGES + 255) / 256, 256, 0, stream>>>(edge_row, edge_col, edge_w,
                                                                 cursor, sorted);

        // ---- 3 layers, wave-per-row gather SpMM ----
        int rows_per_block = 4;                      // 256 threads = 4 waves
        int grid = (N_NODES + rows_per_block - 1) / rows_per_block;

        // layer 0: read inputs directly (srcB pre-offset so srcB + c*EMB works)
        const float* srcB0 = item_emb - (size_t)NUM_USERS * EMB;
        spmm_csr<true, true><<<grid, 256, 0, stream>>>(row_start, sorted,
                                                       user_emb, srcB0, buf0, out);
        // layer 1: buf0 -> buf1
        spmm_csr<false, true><<<grid, 256, 0, stream>>>(row_start, sorted,
                                                        buf0, buf0, buf1, out);
        // layer 2: buf1 -> (acc only)
        spmm_csr<false, false><<<grid, 256, 0, stream>>>(row_start, sorted,
                                                         buf1, buf1, buf0, out);
    } else {
        // ---- fallback: baseline atomic scatter ----
        {
            int blk = 256, g = (TOT4 + blk - 1) / blk;
            concat_init<<<g, blk, 0, stream>>>((const float4*)user_emb, (const float4*)item_emb,
                                               (float4*)buf0, (float4*)out);
        }
        float* cur = buf0;
        float* nxt = buf1;
        for (int l = 0; l < 3; ++l) {
            hipMemsetAsync(nxt, 0, NBUF * sizeof(float), stream);
            int epb = 256 / 64;
            int g = (N_EDGES + epb - 1) / epb;
            spmm_scatter<<<g, 256, 0, stream>>>(edge_row, edge_col, edge_w, cur, nxt);
            int blk = 256, g2 = (TOT4 + blk - 1) / blk;
            acc_scale<<<g2, blk, 0, stream>>>((float4*)out, (const float4*)nxt);
            float* tmp = cur; cur = nxt; nxt = tmp;
        }
    }
}